// Round 11
// baseline (141.811 us; speedup 1.0000x reference)
//
#include <hip/hip_runtime.h>
#include <math.h>

#define BINS 128

// ---------------- ws layout (float units) ----------------
// [0, 16384)       pp      pool partials [(b*64+c)*8+part][16 cells]
// [16384, 16512)   s       sigmoid gate (2, 64)
// [16640, 16642)   mm      mapped uints {min, max}
// [16648, 16776)   ghist   uint[128]

__device__ __forceinline__ unsigned mapf(float f) {
    unsigned u = __float_as_uint(f);
    return (u & 0x80000000u) ? ~u : (u | 0x80000000u);
}
__device__ __forceinline__ float unmapf(unsigned m) {
    unsigned u = (m & 0x80000000u) ? (m & 0x7FFFFFFFu) : ~m;
    return __uint_as_float(u);
}
__device__ __forceinline__ float sel4(float g0, float g1, float g2, float g3, int k) {
    float a = (k & 1) ? g1 : g0;
    float b = (k & 1) ? g3 : g2;
    return (k & 2) ? b : a;
}
// axis coord for trilinear upsample (align_corners=False, 4 -> 64)
__device__ __forceinline__ void axgate(int v, int& lo, int& hi, float& fr) {
    float c = ((float)v + 0.5f) * 0.0625f - 0.5f;
    c = fminf(fmaxf(c, 0.0f), 3.0f);
    int l = (int)floorf(c);
    lo = l; hi = min(l + 1, 3); fr = c - (float)l;
}

// ---- K1: pool partials (R8-proven). 1024 blocks; block = (slab, part). ----
__global__ __launch_bounds__(256) void pool_kernel(const float* __restrict__ x,
                                                   float* __restrict__ pp) {
    const int sb = blockIdx.x;
    const int t = threadIdx.x;
    const float4* xb = (const float4*)x + (size_t)sb * 8192;

    const float4 u0  = xb[ 0*256+t], u1  = xb[ 1*256+t], u2  = xb[ 2*256+t], u3  = xb[ 3*256+t];
    const float4 u4  = xb[ 4*256+t], u5  = xb[ 5*256+t], u6  = xb[ 6*256+t], u7  = xb[ 7*256+t];
    const float4 u8  = xb[ 8*256+t], u9  = xb[ 9*256+t], u10 = xb[10*256+t], u11 = xb[11*256+t];
    const float4 u12 = xb[12*256+t], u13 = xb[13*256+t], u14 = xb[14*256+t], u15 = xb[15*256+t];
    __builtin_amdgcn_sched_barrier(0);
    float a0 = 0.f, a1 = 0.f, a2 = 0.f, a3 = 0.f;
#define ACC(U, A) A += (U.x + U.y) + (U.z + U.w);
    ACC(u0,a0) ACC(u1,a1) ACC(u2,a2) ACC(u3,a3)
    ACC(u4,a0) ACC(u5,a1) ACC(u6,a2) ACC(u7,a3)
    ACC(u8,a0) ACC(u9,a1) ACC(u10,a2) ACC(u11,a3)
    ACC(u12,a0) ACC(u13,a1) ACC(u14,a2) ACC(u15,a3)
    const float4 v0  = xb[16*256+t], v1  = xb[17*256+t], v2  = xb[18*256+t], v3  = xb[19*256+t];
    const float4 v4  = xb[20*256+t], v5  = xb[21*256+t], v6  = xb[22*256+t], v7  = xb[23*256+t];
    const float4 v8  = xb[24*256+t], v9  = xb[25*256+t], v10 = xb[26*256+t], v11 = xb[27*256+t];
    const float4 v12 = xb[28*256+t], v13 = xb[29*256+t], v14 = xb[30*256+t], v15 = xb[31*256+t];
    __builtin_amdgcn_sched_barrier(0);
    ACC(v0,a0) ACC(v1,a1) ACC(v2,a2) ACC(v3,a3)
    ACC(v4,a0) ACC(v5,a1) ACC(v6,a2) ACC(v7,a3)
    ACC(v8,a0) ACC(v9,a1) ACC(v10,a2) ACC(v11,a3)
    ACC(v12,a0) ACC(v13,a1) ACC(v14,a2) ACC(v15,a3)
#undef ACC

    #pragma unroll
    for (int m = 0; m < 4; ++m) {
        const int msk = (m == 0) ? 1 : (m == 1) ? 2 : (m == 2) ? 16 : 32;
        a0 += __shfl_xor(a0, msk); a1 += __shfl_xor(a1, msk);
        a2 += __shfl_xor(a2, msk); a3 += __shfl_xor(a3, msk);
    }
    __shared__ float red[64];
    const int lane = t & 63, wave = t >> 6;
    if (lane < 16 && (lane & 3) == 0) {
        const int pw = lane >> 2;
        red[(0 * 4 + pw) * 4 + wave] = a0;
        red[(1 * 4 + pw) * 4 + wave] = a1;
        red[(2 * 4 + pw) * 4 + wave] = a2;
        red[(3 * 4 + pw) * 4 + wave] = a3;
    }
    __syncthreads();
    if (t < 16)
        pp[sb * 16 + t] = red[t * 4 + 0] + red[t * 4 + 1] + red[t * 4 + 2] + red[t * 4 + 3];
}

// ---- K2: w1 conv (from partials) + InstanceNorm + GELU + w2 conv + sigmoid (R8-proven) ----
__global__ __launch_bounds__(1024) void mid_kernel(const float* __restrict__ pp,
                                                   const float* __restrict__ w1,
                                                   const float* __restrict__ w2,
                                                   float* __restrict__ s_out,
                                                   unsigned* __restrict__ mm,
                                                   unsigned* __restrict__ hist) {
    __shared__ float hs[2 * 8 * 64];
    const int t = threadIdx.x;
    const int b = t >> 9, cm = (t >> 6) & 7, sp = t & 63;
    const int off = (sp >> 4) * 32 + (sp & 15);
    const float* w1r = w1 + cm * 64;
    const float* ppb = pp + b * 64 * 128;
    float h = 0.f;
    for (int c = 0; c < 64; ++c)
        h += w1r[c] * (ppb[c * 128 + off] + ppb[c * 128 + 16 + off]);
    h *= (1.0f / 4096.0f);

    float s1 = h;
    #pragma unroll
    for (int m = 1; m <= 32; m <<= 1) s1 += __shfl_xor(s1, m);
    const float mu = s1 * (1.0f / 64.0f);
    float d = h - mu;
    float s2 = d * d;
    #pragma unroll
    for (int m = 1; m <= 32; m <<= 1) s2 += __shfl_xor(s2, m);
    const float var = s2 * (1.0f / 64.0f);
    const float hn = d / sqrtf(var + 1e-5f);
    hs[(b * 8 + cm) * 64 + sp] = 0.5f * hn * (1.0f + erff(hn * 0.70710678118654752440f));
    __syncthreads();
    if (t < 128) {
        const int bb = t >> 6, ss = t & 63;
        float acc = 0.f;
        #pragma unroll
        for (int c = 0; c < 8; ++c) acc += w2[c] * hs[(bb * 8 + c) * 64 + ss];
        s_out[t] = 1.0f / (1.0f + expf(-acc));
    }
    if (t == 0) { mm[0] = 0xFFFFFFFFu; mm[1] = 0u; }
    if (t >= 128 && t < 256) hist[t - 128] = 0u;
}

// ---------- shared machinery (R9-proven structure) ----------
// 512 blocks, 4 chunks/block, chunk = 4096 float4 = one (b,c,dq) quad.

#define PASS_SETUP()                                                                  \
    const int t = threadIdx.x;                                                        \
    const int bid = blockIdx.x;                                                       \
    const int cbase = (bid & 7) * 256 + (bid >> 3) * 4;                               \
    const int b = cbase >> 10;                                                        \
    if (t < 64) ls64[t] = s[b * 64 + t];                                              \
    int wl0, wh0, wl1, wh1, wl2, wh2, wl3, wh3;                                       \
    float fw0, fw1, fw2, fw3;                                                         \
    {                                                                                 \
        const int wb = (t & 15) * 4;                                                  \
        axgate(wb + 0, wl0, wh0, fw0); axgate(wb + 1, wl1, wh1, fw1);                 \
        axgate(wb + 2, wl2, wh2, fw2); axgate(wb + 3, wl3, wh3, fw3);                 \
    }                                                                                 \
    int hlL, hhL; float fhL; axgate(t & 63, hlL, hhL, fhL);                           \
    const int rbase = t >> 4;

#define ROWG_BUILD(IT)                                                                \
    const int swz = cbase + (IT);                                                     \
    const int dq = swz & 15;                                                          \
    const float4* xp = (const float4*)x + (size_t)swz * 4096;                         \
    __syncthreads();                                                                  \
    {                                                                                 \
        int dl, dh2; float fd; axgate(dq * 4 + (t >> 6), dl, dh2, fd);                \
        const float w00 = (1.f - fd) * (1.f - fhL), w01 = (1.f - fd) * fhL;           \
        const float w10 = fd * (1.f - fhL), w11 = fd * fhL;                           \
        const int i00 = dl * 16 + hlL * 4, i01 = dl * 16 + hhL * 4;                   \
        const int i10 = dh2 * 16 + hlL * 4, i11 = dh2 * 16 + hhL * 4;                 \
        float g0 = w00 * ls64[i00 + 0] + w01 * ls64[i01 + 0] + w10 * ls64[i10 + 0] + w11 * ls64[i11 + 0]; \
        float g1 = w00 * ls64[i00 + 1] + w01 * ls64[i01 + 1] + w10 * ls64[i10 + 1] + w11 * ls64[i11 + 1]; \
        float g2 = w00 * ls64[i00 + 2] + w01 * ls64[i01 + 2] + w10 * ls64[i10 + 2] + w11 * ls64[i11 + 2]; \
        float g3 = w00 * ls64[i00 + 3] + w01 * ls64[i01 + 3] + w10 * ls64[i10 + 3] + w11 * ls64[i11 + 3]; \
        rowg[t] = make_float4(g0, g1, g2, g3);                                        \
    }                                                                                 \
    __syncthreads();

#define GATE4(K, G0, G1, G2, G3)                                                      \
    float G0, G1, G2, G3;                                                             \
    {                                                                                 \
        float4 rg = rowg[(K) * 16 + rbase];                                           \
        float lo, hi;                                                                 \
        lo = sel4(rg.x, rg.y, rg.z, rg.w, wl0); hi = sel4(rg.x, rg.y, rg.z, rg.w, wh0); G0 = lo + fw0 * (hi - lo); \
        lo = sel4(rg.x, rg.y, rg.z, rg.w, wl1); hi = sel4(rg.x, rg.y, rg.z, rg.w, wh1); G1 = lo + fw1 * (hi - lo); \
        lo = sel4(rg.x, rg.y, rg.z, rg.w, wl2); hi = sel4(rg.x, rg.y, rg.z, rg.w, wh2); G2 = lo + fw2 * (hi - lo); \
        lo = sel4(rg.x, rg.y, rg.z, rg.w, wl3); hi = sel4(rg.x, rg.y, rg.z, rg.w, wh3); G3 = lo + fw3 * (hi - lo); \
    }

// ---- K3: global min/max of x * gate (R9-proven). MUST launch with <<<512, 256>>>. ----
__global__ __launch_bounds__(256) void gated_minmax_kernel(const float* __restrict__ x,
                                                           const float* __restrict__ s,
                                                           unsigned* __restrict__ mm) {
    __shared__ float ls64[64];
    __shared__ float4 rowg[256];
    __shared__ float red[8];
    PASS_SETUP()

    float vmin = INFINITY, vmax = -INFINITY;
    #pragma unroll
    for (int it = 0; it < 4; ++it) {
        ROWG_BUILD(it)
        const float4 u0  = xp[ 0*256+t], u1  = xp[ 1*256+t], u2  = xp[ 2*256+t], u3  = xp[ 3*256+t];
        const float4 u4  = xp[ 4*256+t], u5  = xp[ 5*256+t], u6  = xp[ 6*256+t], u7  = xp[ 7*256+t];
        const float4 u8  = xp[ 8*256+t], u9  = xp[ 9*256+t], u10 = xp[10*256+t], u11 = xp[11*256+t];
        const float4 u12 = xp[12*256+t], u13 = xp[13*256+t], u14 = xp[14*256+t], u15 = xp[15*256+t];
        __builtin_amdgcn_sched_barrier(0);
#define MM1(K, U)                                                                     \
        {                                                                             \
            GATE4(K, g0, g1, g2, g3);                                                 \
            float p0 = U.x * g0, p1 = U.y * g1, p2 = U.z * g2, p3 = U.w * g3;         \
            vmin = fminf(vmin, fminf(fminf(p0, p1), fminf(p2, p3)));                  \
            vmax = fmaxf(vmax, fmaxf(fmaxf(p0, p1), fmaxf(p2, p3)));                  \
        }
        MM1(0,u0) MM1(1,u1) MM1(2,u2) MM1(3,u3) MM1(4,u4) MM1(5,u5) MM1(6,u6) MM1(7,u7)
        MM1(8,u8) MM1(9,u9) MM1(10,u10) MM1(11,u11) MM1(12,u12) MM1(13,u13) MM1(14,u14) MM1(15,u15)
#undef MM1
    }

    #pragma unroll
    for (int m = 1; m <= 32; m <<= 1) {
        vmin = fminf(vmin, __shfl_xor(vmin, m));
        vmax = fmaxf(vmax, __shfl_xor(vmax, m));
    }
    const int wave = t >> 6;
    if ((t & 63) == 0) { red[wave] = vmin; red[4 + wave] = vmax; }
    __syncthreads();
    if (t == 0) {
        float m0 = fminf(fminf(red[0], red[1]), fminf(red[2], red[3]));
        float M0 = fmaxf(fmaxf(red[4], red[5]), fmaxf(red[6], red[7]));
        atomicMin(&mm[0], mapf(m0));
        atomicMax(&mm[1], mapf(M0));
    }
}

// ---- K4: 128-bin histogram with wave match-any dedup (leader-only LDS atomics). ----
// Per value slot: 7 ballots build each lane's equal-bin mask; lowest lane adds
// popcount(mask). Cuts LDS atomic lane-ops ~2x (hot-bin concentration).
// Loops NOT fully unrolled to stay within I$. MUST launch with <<<512, 256>>>.
__global__ __launch_bounds__(256) void gated_hist_kernel(const float* __restrict__ x,
                                                         const float* __restrict__ s,
                                                         const unsigned* __restrict__ mm,
                                                         unsigned* __restrict__ ghist) {
    __shared__ float ls64[64];
    __shared__ float4 rowg[256];
    __shared__ unsigned lh[BINS];
    PASS_SETUP()
    if (t < BINS) lh[t] = 0u;

    const float vmin = unmapf(mm[0]);
    const float vmax = unmapf(mm[1]);
    const float inv = 128.0f / (vmax - vmin + 1e-8f);
    const int lane = t & 63;
    const unsigned long long lt = (1ull << lane) - 1ull;

#define HONE(P)                                                                       \
    {                                                                                 \
        int b_ = (int)floorf(((P) - vmin) * inv);                                     \
        b_ = min(max(b_, 0), BINS - 1);                                               \
        unsigned long long m_ = ~0ull;                                                \
        _Pragma("unroll")                                                             \
        for (int j_ = 0; j_ < 7; ++j_) {                                              \
            unsigned long long v_ = __ballot((b_ >> j_) & 1);                         \
            m_ &= ((b_ >> j_) & 1) ? v_ : ~v_;                                        \
        }                                                                             \
        if ((m_ & lt) == 0)                                                           \
            atomicAdd(&lh[b_], (unsigned)__popcll(m_));                               \
    }

    for (int it = 0; it < 4; ++it) {          // chunk loop (not unrolled)
        ROWG_BUILD(it)
        for (int sb2 = 0; sb2 < 4; ++sb2) {   // 4 float4 per sub-batch (not unrolled)
            const int kb = sb2 * 4;
            const float4 u0 = xp[(kb + 0) * 256 + t];
            const float4 u1 = xp[(kb + 1) * 256 + t];
            const float4 u2 = xp[(kb + 2) * 256 + t];
            const float4 u3 = xp[(kb + 3) * 256 + t];
            __builtin_amdgcn_sched_barrier(0);
            {
                GATE4(kb + 0, g0, g1, g2, g3);
                HONE(u0.x * g0) HONE(u0.y * g1) HONE(u0.z * g2) HONE(u0.w * g3)
            }
            {
                GATE4(kb + 1, g0, g1, g2, g3);
                HONE(u1.x * g0) HONE(u1.y * g1) HONE(u1.z * g2) HONE(u1.w * g3)
            }
            {
                GATE4(kb + 2, g0, g1, g2, g3);
                HONE(u2.x * g0) HONE(u2.y * g1) HONE(u2.z * g2) HONE(u2.w * g3)
            }
            {
                GATE4(kb + 3, g0, g1, g2, g3);
                HONE(u3.x * g0) HONE(u3.y * g1) HONE(u3.z * g2) HONE(u3.w * g3)
            }
        }
    }
#undef HONE

    __syncthreads();
    if (t < BINS) {
        unsigned c = lh[t];
        if (c) atomicAdd(&ghist[t], c);
    }
}

// ---- K5: entropy ----
__global__ __launch_bounds__(64) void entropy_kernel(const unsigned* __restrict__ ghist,
                                                     float* __restrict__ out) {
    const int t = threadIdx.x;
    float c0 = (float)ghist[t];
    float c1 = (float)ghist[t + 64];
    float s = c0 + c1;
    #pragma unroll
    for (int m = 1; m <= 32; m <<= 1) s += __shfl_xor(s, m);
    const float inv = 1.0f / (s + 1e-10f);
    float p0 = c0 * inv, p1 = c1 * inv;
    float e = p0 * log2f(p0 + 1e-10f) + p1 * log2f(p1 + 1e-10f);
    #pragma unroll
    for (int m = 1; m <= 32; m <<= 1) e += __shfl_xor(e, m);
    if (t == 0) out[0] = -e;
}

extern "C" void kernel_launch(void* const* d_in, const int* in_sizes, int n_in,
                              void* d_out, int out_size, void* d_ws, size_t ws_size,
                              hipStream_t stream) {
    (void)in_sizes; (void)n_in; (void)out_size; (void)ws_size;
    const float* x  = (const float*)d_in[0];
    const float* w1 = (const float*)d_in[1];
    const float* w2 = (const float*)d_in[2];
    float* out = (float*)d_out;
    float* ws  = (float*)d_ws;

    float* pp       = ws;                      // 16384
    float* s        = ws + 16384;              // 128
    unsigned* mm    = (unsigned*)(ws + 16640); // 2
    unsigned* hist  = (unsigned*)(ws + 16648); // 128

    pool_kernel<<<1024, 256, 0, stream>>>(x, pp);
    mid_kernel<<<1, 1024, 0, stream>>>(pp, w1, w2, s, mm, hist);
    gated_minmax_kernel<<<512, 256, 0, stream>>>(x, s, mm);
    gated_hist_kernel<<<512, 256, 0, stream>>>(x, s, mm, hist);
    entropy_kernel<<<1, 64, 0, stream>>>(hist, out);
}